// Round 1
// baseline (23686.169 us; speedup 1.0000x reference)
//
#include <hip/hip_runtime.h>
#include <math.h>

#define VOCAB 8000
#define EMB   512
#define HID   1024
#define SEQ_L 1024
#define G3    (3*HID)
#define NWG   64          // recurrence workgroups (co-resident: 64 <= 256 CUs)
#define JB    (HID/NWG)   // 16 h-elements owned per WG

// ---------------- prep: dec_in + valid mask ----------------
__global__ __launch_bounds__(1024) void prep_kernel(
    const int* __restrict__ target, const int* __restrict__ sos_p,
    const int* __restrict__ eos_p, int* __restrict__ dec_in,
    float* __restrict__ valid)
{
  int t = threadIdx.x;                    // 1024 threads, 1 block
  int eos = eos_p[0];
  dec_in[t] = (t == 0) ? sos_p[0] : target[t - 1];
  bool ne = (target[t] != eos);
  unsigned long long b = __ballot(ne);
  int lane = t & 63, w = t >> 6;
  __shared__ unsigned long long wb[16];
  if (lane == 0) wb[w] = b;
  __syncthreads();
  // valid[t] = 1 iff target[j] != eos for all j < t  (exclusive prefix-AND)
  bool ok = (((~b) & ((1ull << lane) - 1ull)) == 0ull);
  for (int i = 0; i < 16; i++)
    if (i < w) ok = ok && (wb[i] == ~0ull);
  valid[t] = ok ? 1.0f : 0.0f;
}

// ---------------- fp32 NT GEMM: C[m][n] = dot(A[m][:K], B[n][:K]) + bias[n], x rowscale[m]
// A gathered through idx if idx != null (A row length == K). 128x128 tile, 8x8/thread.
__global__ __launch_bounds__(256) void gemm_nt(
    const float* __restrict__ A, const int* __restrict__ idx,
    const float* __restrict__ B, const float* __restrict__ bias,
    const float* __restrict__ rowscale, float* __restrict__ C,
    int M, int N, int K)
{
  __shared__ __align__(16) float As[16][132];
  __shared__ __align__(16) float Bs[16][132];
  const int tid = threadIdx.x;
  const int bm = blockIdx.y * 128;
  const int bn = blockIdx.x * 128;
  const int tx = tid & 15, ty = tid >> 4;
  float acc[8][8];
#pragma unroll
  for (int i = 0; i < 8; i++)
#pragma unroll
    for (int jj = 0; jj < 8; jj++) acc[i][jj] = 0.f;

  for (int k0 = 0; k0 < K; k0 += 16) {
    __syncthreads();
#pragma unroll
    for (int r = 0; r < 2; r++) {
      int v = tid + 256 * r;
      int row = v >> 2;            // 0..127
      int kq = (v & 3) << 2;       // 0,4,8,12
      int m = bm + row;            // M is always a multiple of 128 here
      const float* abase = idx ? (A + (size_t)idx[m] * K) : (A + (size_t)m * K);
      float4 av = *(const float4*)(abase + k0 + kq);
      As[kq + 0][row] = av.x; As[kq + 1][row] = av.y;
      As[kq + 2][row] = av.z; As[kq + 3][row] = av.w;
      int n = bn + row;
      float4 bv = make_float4(0.f, 0.f, 0.f, 0.f);
      if (n < N) bv = *(const float4*)(B + (size_t)n * K + k0 + kq);
      Bs[kq + 0][row] = bv.x; Bs[kq + 1][row] = bv.y;
      Bs[kq + 2][row] = bv.z; Bs[kq + 3][row] = bv.w;
    }
    __syncthreads();
#pragma unroll
    for (int k = 0; k < 16; k++) {
      float am[8], bb[8];
      *(float4*)&am[0] = *(const float4*)&As[k][ty * 8];
      *(float4*)&am[4] = *(const float4*)&As[k][ty * 8 + 4];
      *(float4*)&bb[0] = *(const float4*)&Bs[k][tx * 8];
      *(float4*)&bb[4] = *(const float4*)&Bs[k][tx * 8 + 4];
#pragma unroll
      for (int i = 0; i < 8; i++)
#pragma unroll
        for (int jj = 0; jj < 8; jj++)
          acc[i][jj] += am[i] * bb[jj];
    }
  }
#pragma unroll
  for (int i = 0; i < 8; i++) {
    int m = bm + ty * 8 + i;
    float rs = rowscale ? rowscale[m] : 1.0f;
#pragma unroll
    for (int jj = 0; jj < 8; jj++) {
      int n = bn + tx * 8 + jj;
      if (n < N) C[(size_t)m * N + n] = (acc[i][jj] + bias[n]) * rs;
    }
  }
}

// ---------------- persistent GRU recurrence: encoder then decoder ----------------
// 64 WGs x 512 threads. WG wg owns h[wg*16 .. wg*16+16) and the 48 matching rows
// of whh (3 gates x 16), held in VGPRs (6 x 4 float4 per thread).
// Thread layout: lane = k-chunk (64 chunks of 16), g = tid>>6 = rowgroup (6 rows each).
// Sync: per-WG flag (own cacheline), release-store / acquire-poll; double-buffered h.
__global__ __launch_bounds__(512, 1) void recur_kernel(
    const float* __restrict__ enc_whh, const float* __restrict__ enc_bhh,
    const float* __restrict__ dec_whh, const float* __restrict__ dec_bhh,
    const float* __restrict__ enc_state, const int* __restrict__ char_seq,
    const float* __restrict__ gi_enc, const float* __restrict__ gi_dec,
    float* __restrict__ hbuf, int* flags, float* __restrict__ hdec)
{
  const int wg   = blockIdx.x;
  const int tid  = threadIdx.x;
  const int lane = tid & 63;
  const int g    = tid >> 6;

  __shared__ __align__(16) float hLDS[HID];
  __shared__ float ghLDS[3 * JB];

  // init: publish h0 slice (parity 0), then flag = 0  (ws poison 0xAA.. is negative -> spins block until real 0)
  if (tid < JB) hbuf[wg * JB + tid] = enc_state[wg * JB + tid];
  __threadfence();
  __syncthreads();
  if (tid == 0)
    __hip_atomic_store(&flags[wg * 32], 0, __ATOMIC_RELEASE, __HIP_MEMORY_SCOPE_AGENT);

  // encoder weights -> registers
  float4 wreg[6][4];
#pragma unroll
  for (int q = 0; q < 6; q++) {
    int rr  = g * 6 + q;                                   // rr = gate*16 + jloc
    int row = (rr >> 4) * HID + wg * JB + (rr & 15);
#pragma unroll
    for (int u = 0; u < 4; u++)
      wreg[q][u] = *(const float4*)(enc_whh + (size_t)row * HID + lane * 16 + u * 4);
  }
  const int j = wg * JB + (tid & (JB - 1));                // used by tid < 16
  float bhr = enc_bhh[j], bhz = enc_bhh[HID + j], bhn = enc_bhh[2 * HID + j];

  for (int s = 1; s <= 2 * SEQ_L; s++) {
    if (s == SEQ_L + 1) {                                  // switch to decoder weights
#pragma unroll
      for (int q = 0; q < 6; q++) {
        int rr  = g * 6 + q;
        int row = (rr >> 4) * HID + wg * JB + (rr & 15);
#pragma unroll
        for (int u = 0; u < 4; u++)
          wreg[q][u] = *(const float4*)(dec_whh + (size_t)row * HID + lane * 16 + u * 4);
      }
      bhr = dec_bhh[j]; bhz = dec_bhh[HID + j]; bhn = dec_bhh[2 * HID + j];
    }
    // prefetch gi + mask before the spin (loads in flight while waiting)
    float gir = 0.f, giz = 0.f, gin = 0.f;
    int cs = 1;
    if (tid < JB) {
      const float* gi = (s <= SEQ_L) ? (gi_enc + (size_t)(s - 1) * G3)
                                     : (gi_dec + (size_t)(s - SEQ_L - 1) * G3);
      gir = gi[j]; giz = gi[HID + j]; gin = gi[2 * HID + j];
      if (s <= SEQ_L) cs = char_seq[s - 1];
    }
    // wait until every WG has published h_{s-1}
    if (tid < 64) {
      const int tgt = s - 1;
      while (true) {
        int v = __hip_atomic_load(&flags[tid * 32], __ATOMIC_ACQUIRE, __HIP_MEMORY_SCOPE_AGENT);
        if (__ballot(v < tgt) == 0ull) break;
        __builtin_amdgcn_s_sleep(1);
      }
    }
    __syncthreads();
    // stage h_{s-1} into LDS
    const float* hsrc = hbuf + ((s - 1) & 1) * HID;
    hLDS[tid]       = hsrc[tid];
    hLDS[tid + 512] = hsrc[tid + 512];
    __syncthreads();
    // gh = whh_slice @ h   (96 FMA/thread, then 64-lane butterfly reduce)
    const float4* h4 = (const float4*)&hLDS[lane * 16];
    float4 hreg[4];
#pragma unroll
    for (int u = 0; u < 4; u++) hreg[u] = h4[u];
    float acc[6];
#pragma unroll
    for (int q = 0; q < 6; q++) {
      float a = 0.f;
#pragma unroll
      for (int u = 0; u < 4; u++) {
        a += wreg[q][u].x * hreg[u].x;
        a += wreg[q][u].y * hreg[u].y;
        a += wreg[q][u].z * hreg[u].z;
        a += wreg[q][u].w * hreg[u].w;
      }
      acc[q] = a;
    }
#pragma unroll
    for (int m = 1; m < 64; m <<= 1) {
#pragma unroll
      for (int q = 0; q < 6; q++)
        acc[q] += __shfl_xor(acc[q], m, 64);
    }
    if (lane == 0) {
#pragma unroll
      for (int q = 0; q < 6; q++) ghLDS[g * 6 + q] = acc[q];
    }
    __syncthreads();
    // GRU elementwise for owned slice (PyTorch GRUCell: r,z,n order; bhh_n inside r*( ))
    if (tid < JB) {
      float ghr = ghLDS[tid]          + bhr;
      float ghz = ghLDS[JB + tid]     + bhz;
      float ghn = ghLDS[2 * JB + tid] + bhn;
      float r = 1.f / (1.f + __expf(-(gir + ghr)));
      float z = 1.f / (1.f + __expf(-(giz + ghz)));
      float n = tanhf(gin + r * ghn);
      float hold = hLDS[j];
      float hnew = (1.f - z) * n + z * hold;
      if (s <= SEQ_L && cs == 0) hnew = hold;             // encoder: masked state update
      hbuf[(s & 1) * HID + j] = hnew;
      if (s > SEQ_L) hdec[(size_t)(s - SEQ_L - 1) * HID + j] = hnew;
    }
    __threadfence();
    __syncthreads();
    if (tid == 0)
      __hip_atomic_store(&flags[wg * 32], s, __ATOMIC_RELEASE, __HIP_MEMORY_SCOPE_AGENT);
  }
}

// ---------------- states output: hdec * valid ----------------
__global__ __launch_bounds__(256) void states_kernel(
    const float* __restrict__ hdec, const float* __restrict__ valid,
    float* __restrict__ out2)
{
  int i = blockIdx.x * 256 + threadIdx.x;
  out2[i] = hdec[i] * valid[i >> 10];
}

extern "C" void kernel_launch(void* const* d_in, const int* in_sizes, int n_in,
                              void* d_out, int out_size, void* d_ws, size_t ws_size,
                              hipStream_t stream)
{
  const int*   char_seq  = (const int*)  d_in[0];
  const int*   target    = (const int*)  d_in[1];
  const float* enc_state = (const float*)d_in[2];
  const float* emb       = (const float*)d_in[3];
  const float* enc_wih   = (const float*)d_in[4];
  const float* enc_whh   = (const float*)d_in[5];
  const float* enc_bih   = (const float*)d_in[6];
  const float* enc_bhh   = (const float*)d_in[7];
  const float* dec_wih   = (const float*)d_in[8];
  const float* dec_whh   = (const float*)d_in[9];
  const float* dec_bih   = (const float*)d_in[10];
  const float* dec_bhh   = (const float*)d_in[11];
  const float* out_w     = (const float*)d_in[12];
  const float* out_b     = (const float*)d_in[13];
  const int*   sos_p     = (const int*)  d_in[14];
  const int*   eos_p     = (const int*)  d_in[15];

  char* ws = (char*)d_ws;
  float* gi_enc = (float*)ws;  ws += (size_t)SEQ_L * G3 * sizeof(float);
  float* gi_dec = (float*)ws;  ws += (size_t)SEQ_L * G3 * sizeof(float);
  float* hdec   = (float*)ws;  ws += (size_t)SEQ_L * HID * sizeof(float);
  float* hbuf   = (float*)ws;  ws += 2 * HID * sizeof(float);
  float* valid  = (float*)ws;  ws += SEQ_L * sizeof(float);
  int*   dec_in = (int*)ws;    ws += SEQ_L * sizeof(int);
  int*   flags  = (int*)ws;    ws += NWG * 32 * sizeof(int);

  float* out_scores = (float*)d_out;
  float* out_states = out_scores + (size_t)SEQ_L * VOCAB;

  prep_kernel<<<1, 1024, 0, stream>>>(target, sos_p, eos_p, dec_in, valid);
  gemm_nt<<<dim3(G3 / 128, SEQ_L / 128), 256, 0, stream>>>(
      emb, char_seq, enc_wih, enc_bih, nullptr, gi_enc, SEQ_L, G3, EMB);
  gemm_nt<<<dim3(G3 / 128, SEQ_L / 128), 256, 0, stream>>>(
      emb, dec_in, dec_wih, dec_bih, nullptr, gi_dec, SEQ_L, G3, EMB);
  recur_kernel<<<NWG, 512, 0, stream>>>(
      enc_whh, enc_bhh, dec_whh, dec_bhh, enc_state, char_seq,
      gi_enc, gi_dec, hbuf, flags, hdec);
  gemm_nt<<<dim3((VOCAB + 127) / 128, SEQ_L / 128), 256, 0, stream>>>(
      hdec, nullptr, out_w, out_b, valid, out_scores, SEQ_L, VOCAB, HID);
  states_kernel<<<(SEQ_L * HID) / 256, 256, 0, stream>>>(hdec, valid, out_states);
}

// Round 2
// 5701.952 us; speedup vs baseline: 4.1540x; 4.1540x over previous
//
#include <hip/hip_runtime.h>
#include <math.h>

#define VOCAB 8000
#define EMB   512
#define HID   1024
#define SEQ_L 1024
#define G3    (3*HID)
#define NWG   64          // recurrence workgroups (co-resident: 64 <= 256 CUs)
#define JB    (HID/NWG)   // 16 h-elements owned per WG
#define POISON 0xAAAAAAAAu

// ---------------- prep: dec_in + valid mask ----------------
__global__ __launch_bounds__(1024) void prep_kernel(
    const int* __restrict__ target, const int* __restrict__ sos_p,
    const int* __restrict__ eos_p, int* __restrict__ dec_in,
    float* __restrict__ valid)
{
  int t = threadIdx.x;                    // 1024 threads, 1 block
  int eos = eos_p[0];
  dec_in[t] = (t == 0) ? sos_p[0] : target[t - 1];
  bool ne = (target[t] != eos);
  unsigned long long b = __ballot(ne);
  int lane = t & 63, w = t >> 6;
  __shared__ unsigned long long wb[16];
  if (lane == 0) wb[w] = b;
  __syncthreads();
  // valid[t] = 1 iff target[j] != eos for all j < t  (exclusive prefix-AND)
  bool ok = (((~b) & ((1ull << lane) - 1ull)) == 0ull);
  for (int i = 0; i < 16; i++)
    if (i < w) ok = ok && (wb[i] == ~0ull);
  valid[t] = ok ? 1.0f : 0.0f;
}

// ---------------- fp32 NT GEMM: C[m][n] = dot(A[m][:K], B[n][:K]) + bias[n], x rowscale[m]
__global__ __launch_bounds__(256) void gemm_nt(
    const float* __restrict__ A, const int* __restrict__ idx,
    const float* __restrict__ B, const float* __restrict__ bias,
    const float* __restrict__ rowscale, float* __restrict__ C,
    int M, int N, int K)
{
  __shared__ __align__(16) float As[16][132];
  __shared__ __align__(16) float Bs[16][132];
  const int tid = threadIdx.x;
  const int bm = blockIdx.y * 128;
  const int bn = blockIdx.x * 128;
  const int tx = tid & 15, ty = tid >> 4;
  float acc[8][8];
#pragma unroll
  for (int i = 0; i < 8; i++)
#pragma unroll
    for (int jj = 0; jj < 8; jj++) acc[i][jj] = 0.f;

  for (int k0 = 0; k0 < K; k0 += 16) {
    __syncthreads();
#pragma unroll
    for (int r = 0; r < 2; r++) {
      int v = tid + 256 * r;
      int row = v >> 2;            // 0..127
      int kq = (v & 3) << 2;       // 0,4,8,12
      int m = bm + row;            // M is always a multiple of 128 here
      const float* abase = idx ? (A + (size_t)idx[m] * K) : (A + (size_t)m * K);
      float4 av = *(const float4*)(abase + k0 + kq);
      As[kq + 0][row] = av.x; As[kq + 1][row] = av.y;
      As[kq + 2][row] = av.z; As[kq + 3][row] = av.w;
      int n = bn + row;
      float4 bv = make_float4(0.f, 0.f, 0.f, 0.f);
      if (n < N) bv = *(const float4*)(B + (size_t)n * K + k0 + kq);
      Bs[kq + 0][row] = bv.x; Bs[kq + 1][row] = bv.y;
      Bs[kq + 2][row] = bv.z; Bs[kq + 3][row] = bv.w;
    }
    __syncthreads();
#pragma unroll
    for (int k = 0; k < 16; k++) {
      float am[8], bb[8];
      *(float4*)&am[0] = *(const float4*)&As[k][ty * 8];
      *(float4*)&am[4] = *(const float4*)&As[k][ty * 8 + 4];
      *(float4*)&bb[0] = *(const float4*)&Bs[k][tx * 8];
      *(float4*)&bb[4] = *(const float4*)&Bs[k][tx * 8 + 4];
#pragma unroll
      for (int i = 0; i < 8; i++)
#pragma unroll
        for (int jj = 0; jj < 8; jj++)
          acc[i][jj] += am[i] * bb[jj];
    }
  }
#pragma unroll
  for (int i = 0; i < 8; i++) {
    int m = bm + ty * 8 + i;
    float rs = rowscale ? rowscale[m] : 1.0f;
#pragma unroll
    for (int jj = 0; jj < 8; jj++) {
      int n = bn + tx * 8 + jj;
      if (n < N) C[(size_t)m * N + n] = (acc[i][jj] + bias[n]) * rs;
    }
  }
}

// ---------------- persistent GRU recurrence: fence-free poison-polling handoff ----
// hbuf: (2*SEQ_L+1) x HID rows; row s = h after s steps; row 0 = h0.
// Producer publishes via atomicExch (executes at Infinity Cache -> globally
// visible, no L2 writeback needed). Consumers poll row s-1 dwords with relaxed
// agent-scope loads (sc1 -> read IC, bypass stale L2/L1) until != 0xAAAAAAAA
// (harness re-poisons d_ws before every launch). No fences, no flags.
__global__ __launch_bounds__(512, 1) void recur_kernel(
    const float* __restrict__ enc_whh, const float* __restrict__ enc_bhh,
    const float* __restrict__ dec_whh, const float* __restrict__ dec_bhh,
    const float* __restrict__ enc_state, const int* __restrict__ char_seq,
    const float* __restrict__ gi_enc, const float* __restrict__ gi_dec,
    float* hbuf)
{
  const int wg   = blockIdx.x;
  const int tid  = threadIdx.x;
  const int lane = tid & 63;
  const int g    = tid >> 6;

  __shared__ __align__(16) float hLDS[HID];
  __shared__ float ghLDS[3 * JB];

  // publish h0 slice (anti-poison squash: nudge 1 ulp if value == poison pattern)
  if (tid < JB) {
    float v = enc_state[wg * JB + tid];
    if (__float_as_uint(v) == POISON) v = __uint_as_float(POISON ^ 1u);
    atomicExch(&hbuf[wg * JB + tid], v);
  }

  // encoder weights -> registers (48 rows of whh per WG, 6 rows x 16-chunk per thread)
  float4 wreg[6][4];
#pragma unroll
  for (int q = 0; q < 6; q++) {
    int rr  = g * 6 + q;                                   // rr = gate*16 + jloc
    int row = (rr >> 4) * HID + wg * JB + (rr & 15);
#pragma unroll
    for (int u = 0; u < 4; u++)
      wreg[q][u] = *(const float4*)(enc_whh + (size_t)row * HID + lane * 16 + u * 4);
  }
  const int j = wg * JB + (tid & (JB - 1));                // used by tid < 16
  float bhr = enc_bhh[j], bhz = enc_bhh[HID + j], bhn = enc_bhh[2 * HID + j];

  for (int s = 1; s <= 2 * SEQ_L; s++) {
    if (s == SEQ_L + 1) {                                  // switch to decoder weights
#pragma unroll
      for (int q = 0; q < 6; q++) {
        int rr  = g * 6 + q;
        int row = (rr >> 4) * HID + wg * JB + (rr & 15);
#pragma unroll
        for (int u = 0; u < 4; u++)
          wreg[q][u] = *(const float4*)(dec_whh + (size_t)row * HID + lane * 16 + u * 4);
      }
      bhr = dec_bhh[j]; bhz = dec_bhh[HID + j]; bhn = dec_bhh[2 * HID + j];
    }
    // prefetch gi + mask (plain loads, L2-warm) before the poll
    float gir = 0.f, giz = 0.f, gin = 0.f;
    int cs = 1;
    if (tid < JB) {
      const float* gi = (s <= SEQ_L) ? (gi_enc + (size_t)(s - 1) * G3)
                                     : (gi_dec + (size_t)(s - SEQ_L - 1) * G3);
      gir = gi[j]; giz = gi[HID + j]; gin = gi[2 * HID + j];
      if (s <= SEQ_L) cs = char_seq[s - 1];
    }
    // poll h_{s-1}: thread t owns dwords {t, t+512} of the row
    const float* hp = hbuf + (size_t)(s - 1) * HID;
    float a = __hip_atomic_load(&hp[tid],       __ATOMIC_RELAXED, __HIP_MEMORY_SCOPE_AGENT);
    float b = __hip_atomic_load(&hp[tid + 512], __ATOMIC_RELAXED, __HIP_MEMORY_SCOPE_AGENT);
    while (__float_as_uint(a) == POISON)
      a = __hip_atomic_load(&hp[tid],       __ATOMIC_RELAXED, __HIP_MEMORY_SCOPE_AGENT);
    while (__float_as_uint(b) == POISON)
      b = __hip_atomic_load(&hp[tid + 512], __ATOMIC_RELAXED, __HIP_MEMORY_SCOPE_AGENT);
    hLDS[tid]       = a;
    hLDS[tid + 512] = b;
    __syncthreads();
    // read hold BEFORE the second barrier (hLDS may be overwritten by early pollers after it)
    float hold = (tid < JB) ? hLDS[j] : 0.f;
    // gh = whh_slice @ h   (96 FMA/thread, then 64-lane butterfly reduce)
    const float4* h4 = (const float4*)&hLDS[lane * 16];
    float4 hreg[4];
#pragma unroll
    for (int u = 0; u < 4; u++) hreg[u] = h4[u];
    float acc[6];
#pragma unroll
    for (int q = 0; q < 6; q++) {
      float aq = 0.f;
#pragma unroll
      for (int u = 0; u < 4; u++) {
        aq += wreg[q][u].x * hreg[u].x;
        aq += wreg[q][u].y * hreg[u].y;
        aq += wreg[q][u].z * hreg[u].z;
        aq += wreg[q][u].w * hreg[u].w;
      }
      acc[q] = aq;
    }
#pragma unroll
    for (int m = 1; m < 64; m <<= 1) {
#pragma unroll
      for (int q = 0; q < 6; q++)
        acc[q] += __shfl_xor(acc[q], m, 64);
    }
    if (lane == 0) {
#pragma unroll
      for (int q = 0; q < 6; q++) ghLDS[g * 6 + q] = acc[q];
    }
    __syncthreads();
    // GRU elementwise for owned slice; publish h_s via atomicExch (lands at IC)
    if (tid < JB) {
      float ghr = ghLDS[tid]          + bhr;
      float ghz = ghLDS[JB + tid]     + bhz;
      float ghn = ghLDS[2 * JB + tid] + bhn;
      float r = 1.f / (1.f + __expf(-(gir + ghr)));
      float z = 1.f / (1.f + __expf(-(giz + ghz)));
      float n = tanhf(gin + r * ghn);
      float hnew = (1.f - z) * n + z * hold;
      if (s <= SEQ_L && cs == 0) hnew = hold;             // encoder: masked state update
      if (__float_as_uint(hnew) == POISON) hnew = __uint_as_float(POISON ^ 1u);
      atomicExch(&hbuf[(size_t)s * HID + j], hnew);
    }
    // no end-of-step barrier needed: next step's hLDS writes are gated by the
    // poll (which can't complete until after this step's stores), and all hLDS
    // reads of this step precede the second __syncthreads above.
  }
}

// ---------------- states output: hdec * valid ----------------
__global__ __launch_bounds__(256) void states_kernel(
    const float* __restrict__ hdec, const float* __restrict__ valid,
    float* __restrict__ out2)
{
  int i = blockIdx.x * 256 + threadIdx.x;
  out2[i] = hdec[i] * valid[i >> 10];
}

extern "C" void kernel_launch(void* const* d_in, const int* in_sizes, int n_in,
                              void* d_out, int out_size, void* d_ws, size_t ws_size,
                              hipStream_t stream)
{
  const int*   char_seq  = (const int*)  d_in[0];
  const int*   target    = (const int*)  d_in[1];
  const float* enc_state = (const float*)d_in[2];
  const float* emb       = (const float*)d_in[3];
  const float* enc_wih   = (const float*)d_in[4];
  const float* enc_whh   = (const float*)d_in[5];
  const float* enc_bih   = (const float*)d_in[6];
  const float* enc_bhh   = (const float*)d_in[7];
  const float* dec_wih   = (const float*)d_in[8];
  const float* dec_whh   = (const float*)d_in[9];
  const float* dec_bih   = (const float*)d_in[10];
  const float* dec_bhh   = (const float*)d_in[11];
  const float* out_w     = (const float*)d_in[12];
  const float* out_b     = (const float*)d_in[13];
  const int*   sos_p     = (const int*)  d_in[14];
  const int*   eos_p     = (const int*)  d_in[15];

  char* ws = (char*)d_ws;
  float* gi_enc = (float*)ws;  ws += (size_t)SEQ_L * G3 * sizeof(float);
  float* gi_dec = (float*)ws;  ws += (size_t)SEQ_L * G3 * sizeof(float);
  float* hbuf   = (float*)ws;  ws += (size_t)(2 * SEQ_L + 1) * HID * sizeof(float);
  float* valid  = (float*)ws;  ws += SEQ_L * sizeof(float);
  int*   dec_in = (int*)ws;    ws += SEQ_L * sizeof(int);

  // decode step d (1..SEQ_L) writes hbuf row SEQ_L+d  ->  hdec row d-1 = hbuf[SEQ_L+1]
  float* hdec = hbuf + (size_t)(SEQ_L + 1) * HID;

  float* out_scores = (float*)d_out;
  float* out_states = out_scores + (size_t)SEQ_L * VOCAB;

  prep_kernel<<<1, 1024, 0, stream>>>(target, sos_p, eos_p, dec_in, valid);
  gemm_nt<<<dim3(G3 / 128, SEQ_L / 128), 256, 0, stream>>>(
      emb, char_seq, enc_wih, enc_bih, nullptr, gi_enc, SEQ_L, G3, EMB);
  gemm_nt<<<dim3(G3 / 128, SEQ_L / 128), 256, 0, stream>>>(
      emb, dec_in, dec_wih, dec_bih, nullptr, gi_dec, SEQ_L, G3, EMB);
  recur_kernel<<<NWG, 512, 0, stream>>>(
      enc_whh, enc_bhh, dec_whh, dec_bhh, enc_state, char_seq,
      gi_enc, gi_dec, hbuf);
  gemm_nt<<<dim3((VOCAB + 127) / 128, SEQ_L / 128), 256, 0, stream>>>(
      hdec, nullptr, out_w, out_b, valid, out_scores, SEQ_L, VOCAB, HID);
  states_kernel<<<(SEQ_L * HID) / 256, 256, 0, stream>>>(hdec, valid, out_states);
}

// Round 3
// 5343.063 us; speedup vs baseline: 4.4331x; 1.0672x over previous
//
#include <hip/hip_runtime.h>
#include <math.h>

#define VOCAB 8000
#define EMB   512
#define HID   1024
#define SEQ_L 1024
#define G3    (3*HID)
#define NWG   64          // recurrence workgroups (co-resident: 64 <= 256 CUs)
#define JB    (HID/NWG)   // 16 h-elements owned per WG
#define POISON 0xAAAAAAAAu

typedef float v2f __attribute__((ext_vector_type(2)));

// ---------------- prep: dec_in + valid mask ----------------
__global__ __launch_bounds__(1024) void prep_kernel(
    const int* __restrict__ target, const int* __restrict__ sos_p,
    const int* __restrict__ eos_p, int* __restrict__ dec_in,
    float* __restrict__ valid)
{
  int t = threadIdx.x;                    // 1024 threads, 1 block
  int eos = eos_p[0];
  dec_in[t] = (t == 0) ? sos_p[0] : target[t - 1];
  bool ne = (target[t] != eos);
  unsigned long long b = __ballot(ne);
  int lane = t & 63, w = t >> 6;
  __shared__ unsigned long long wb[16];
  if (lane == 0) wb[w] = b;
  __syncthreads();
  // valid[t] = 1 iff target[j] != eos for all j < t  (exclusive prefix-AND)
  bool ok = (((~b) & ((1ull << lane) - 1ull)) == 0ull);
  for (int i = 0; i < 16; i++)
    if (i < w) ok = ok && (wb[i] == ~0ull);
  valid[t] = ok ? 1.0f : 0.0f;
}

// ---------------- fp32 NT GEMM: C[m][n] = dot(A[m][:K], B[n][:K]) + bias[n], x rowscale[m]
__global__ __launch_bounds__(256) void gemm_nt(
    const float* __restrict__ A, const int* __restrict__ idx,
    const float* __restrict__ B, const float* __restrict__ bias,
    const float* __restrict__ rowscale, float* __restrict__ C,
    int M, int N, int K)
{
  __shared__ __align__(16) float As[16][132];
  __shared__ __align__(16) float Bs[16][132];
  const int tid = threadIdx.x;
  const int bm = blockIdx.y * 128;
  const int bn = blockIdx.x * 128;
  const int tx = tid & 15, ty = tid >> 4;
  float acc[8][8];
#pragma unroll
  for (int i = 0; i < 8; i++)
#pragma unroll
    for (int jj = 0; jj < 8; jj++) acc[i][jj] = 0.f;

  for (int k0 = 0; k0 < K; k0 += 16) {
    __syncthreads();
#pragma unroll
    for (int r = 0; r < 2; r++) {
      int v = tid + 256 * r;
      int row = v >> 2;            // 0..127
      int kq = (v & 3) << 2;       // 0,4,8,12
      int m = bm + row;            // M is always a multiple of 128 here
      const float* abase = idx ? (A + (size_t)idx[m] * K) : (A + (size_t)m * K);
      float4 av = *(const float4*)(abase + k0 + kq);
      As[kq + 0][row] = av.x; As[kq + 1][row] = av.y;
      As[kq + 2][row] = av.z; As[kq + 3][row] = av.w;
      int n = bn + row;
      float4 bv = make_float4(0.f, 0.f, 0.f, 0.f);
      if (n < N) bv = *(const float4*)(B + (size_t)n * K + k0 + kq);
      Bs[kq + 0][row] = bv.x; Bs[kq + 1][row] = bv.y;
      Bs[kq + 2][row] = bv.z; Bs[kq + 3][row] = bv.w;
    }
    __syncthreads();
#pragma unroll
    for (int k = 0; k < 16; k++) {
      float am[8], bb[8];
      *(float4*)&am[0] = *(const float4*)&As[k][ty * 8];
      *(float4*)&am[4] = *(const float4*)&As[k][ty * 8 + 4];
      *(float4*)&bb[0] = *(const float4*)&Bs[k][tx * 8];
      *(float4*)&bb[4] = *(const float4*)&Bs[k][tx * 8 + 4];
#pragma unroll
      for (int i = 0; i < 8; i++)
#pragma unroll
        for (int jj = 0; jj < 8; jj++)
          acc[i][jj] += am[i] * bb[jj];
    }
  }
#pragma unroll
  for (int i = 0; i < 8; i++) {
    int m = bm + ty * 8 + i;
    float rs = rowscale ? rowscale[m] : 1.0f;
#pragma unroll
    for (int jj = 0; jj < 8; jj++) {
      int n = bn + tx * 8 + jj;
      if (n < N) C[(size_t)m * N + n] = (acc[i][jj] + bias[n]) * rs;
    }
  }
}

// ---------------- persistent GRU recurrence -------------------------------
// 64 WGs x 1024 threads. Fence-free poison-polling handoff through hbuf
// ((2*SEQ_L+1) x HID rows; row s = h after s steps). atomicExch publishes at
// the Infinity Cache; relaxed agent loads poll; future rows are pre-warmed
// into IC via atomicOr(x,0) so neither side pays an HBM cold miss.
// Thread layout: wave w (0..15) owns whh rows rr = 3w..3w+2; lane handles
// k-columns {u*64+lane, u=0..15} -> conflict-free ds_read_b32, coalesced
// weight loads, 48 weight VGPRs/thread (no spill).
__global__ __launch_bounds__(1024, 1) void recur_kernel(
    const float* __restrict__ enc_whh, const float* __restrict__ enc_bhh,
    const float* __restrict__ dec_whh, const float* __restrict__ dec_bhh,
    const float* __restrict__ enc_state, const int* __restrict__ char_seq,
    const float* __restrict__ gi_enc, const float* __restrict__ gi_dec,
    float* hbuf)
{
  const int wg   = blockIdx.x;
  const int tid  = threadIdx.x;
  const int lane = tid & 63;
  const int w    = tid >> 6;            // wave id 0..15

  __shared__ __align__(16) float hLDS[HID];
  __shared__ float ghLDS[3 * JB];

  // publish h0 slice (anti-poison squash: nudge 1 ulp if value == poison)
  if (tid < JB) {
    float v = enc_state[wg * JB + tid];
    if (__float_as_uint(v) == POISON) v = __uint_as_float(POISON ^ 1u);
    atomicExch(&hbuf[wg * JB + tid], v);
  }
  // warm rows 1..8 (allocate our slice's line at IC; atomicOr(x,0) is a no-op RMW)
  if (tid >= 977 && tid <= 984) {
    int row = tid - 976;
    atomicOr((unsigned int*)&hbuf[(size_t)row * HID + wg * JB], 0u);
  }

  // weights -> registers: wv[r][u] packs k = u*64+lane and (u+8)*64+lane
  v2f wv[3][8];
#pragma unroll
  for (int r = 0; r < 3; r++) {
    int rr  = w * 3 + r;                                   // rr = gate*16 + jloc
    const float* wrow = enc_whh + (size_t)((rr >> 4) * HID + wg * JB + (rr & 15)) * HID;
#pragma unroll
    for (int u = 0; u < 8; u++) {
      wv[r][u].x = wrow[u * 64 + lane];
      wv[r][u].y = wrow[(u + 8) * 64 + lane];
    }
  }
  const int j = wg * JB + (tid & (JB - 1));                // used by tid < 16
  float bhr = enc_bhh[j], bhz = enc_bhh[HID + j], bhn = enc_bhh[2 * HID + j];

  for (int s = 1; s <= 2 * SEQ_L; s++) {
    if (s == SEQ_L + 1) {                                  // switch to decoder weights
#pragma unroll
      for (int r = 0; r < 3; r++) {
        int rr  = w * 3 + r;
        const float* wrow = dec_whh + (size_t)((rr >> 4) * HID + wg * JB + (rr & 15)) * HID;
#pragma unroll
        for (int u = 0; u < 8; u++) {
          wv[r][u].x = wrow[u * 64 + lane];
          wv[r][u].y = wrow[(u + 8) * 64 + lane];
        }
      }
      bhr = dec_bhh[j]; bhz = dec_bhh[HID + j]; bhn = dec_bhh[2 * HID + j];
    }
    // warm row s+8 (off critical path, wave 15)
    if (tid == 976 && s + 8 <= 2 * SEQ_L)
      atomicOr((unsigned int*)&hbuf[(size_t)(s + 8) * HID + wg * JB], 0u);
    // prefetch gi + mask (plain loads, issued before the poll)
    float gir = 0.f, giz = 0.f, gin = 0.f;
    int cs = 1;
    if (tid < JB) {
      const float* gi = (s <= SEQ_L) ? (gi_enc + (size_t)(s - 1) * G3)
                                     : (gi_dec + (size_t)(s - SEQ_L - 1) * G3);
      gir = gi[j]; giz = gi[HID + j]; gin = gi[2 * HID + j];
      if (s <= SEQ_L) cs = char_seq[s - 1];
    }
    // poll h_{s-1}: thread t owns dword t of the row
    const float* hp = hbuf + (size_t)(s - 1) * HID;
    float a = __hip_atomic_load(&hp[tid], __ATOMIC_RELAXED, __HIP_MEMORY_SCOPE_AGENT);
    while (__float_as_uint(a) == POISON)
      a = __hip_atomic_load(&hp[tid], __ATOMIC_RELAXED, __HIP_MEMORY_SCOPE_AGENT);
    hLDS[tid] = a;
    __syncthreads();
    // hold for owned slice (read before anyone can overwrite hLDS next iter;
    // next-iter writes are gated by our own publish of row s)
    float hold = (tid < JB) ? hLDS[j] : 0.f;
    // h fragments: k = u*64+lane -> conflict-free b32 reads
    float hs[16];
#pragma unroll
    for (int u = 0; u < 16; u++) hs[u] = hLDS[u * 64 + lane];
    // 3 rows x 16 MACs as packed fp32
    float acc3[3];
#pragma unroll
    for (int r = 0; r < 3; r++) {
      v2f a2 = {0.f, 0.f};
#pragma unroll
      for (int u = 0; u < 8; u++) {
        v2f h2 = {hs[u], hs[u + 8]};
        a2 = __builtin_elementwise_fma(wv[r][u], h2, a2);
      }
      acc3[r] = a2.x + a2.y;
    }
#pragma unroll
    for (int m = 1; m < 64; m <<= 1) {
#pragma unroll
      for (int r = 0; r < 3; r++)
        acc3[r] += __shfl_xor(acc3[r], m, 64);
    }
    if (lane == 0) {
#pragma unroll
      for (int r = 0; r < 3; r++) ghLDS[w * 3 + r] = acc3[r];
    }
    __syncthreads();
    // GRU elementwise for owned slice; publish h_s via atomicExch (lands at IC)
    if (tid < JB) {
      float ghr = ghLDS[tid]      + bhr;
      float ghz = ghLDS[JB + tid] + bhz;   // ghLDS indexed by rr = gate*16+jloc
      float ghn = ghLDS[2 * JB + tid] + bhn;
      float r = 1.f / (1.f + __expf(-(gir + ghr)));
      float z = 1.f / (1.f + __expf(-(giz + ghz)));
      float n = tanhf(gin + r * ghn);
      float hnew = (1.f - z) * n + z * hold;
      if (s <= SEQ_L && cs == 0) hnew = hold;             // encoder: masked state update
      if (__float_as_uint(hnew) == POISON) hnew = __uint_as_float(POISON ^ 1u);
      atomicExch(&hbuf[(size_t)s * HID + j], hnew);
    }
    // no end-of-step barrier: next iter's hLDS writes are gated by the poll,
    // which cannot complete before this WG's own publish of row s.
  }
}

// ---------------- states output: hdec * valid ----------------
__global__ __launch_bounds__(256) void states_kernel(
    const float* __restrict__ hdec, const float* __restrict__ valid,
    float* __restrict__ out2)
{
  int i = blockIdx.x * 256 + threadIdx.x;
  out2[i] = hdec[i] * valid[i >> 10];
}

extern "C" void kernel_launch(void* const* d_in, const int* in_sizes, int n_in,
                              void* d_out, int out_size, void* d_ws, size_t ws_size,
                              hipStream_t stream)
{
  const int*   char_seq  = (const int*)  d_in[0];
  const int*   target    = (const int*)  d_in[1];
  const float* enc_state = (const float*)d_in[2];
  const float* emb       = (const float*)d_in[3];
  const float* enc_wih   = (const float*)d_in[4];
  const float* enc_whh   = (const float*)d_in[5];
  const float* enc_bih   = (const float*)d_in[6];
  const float* enc_bhh   = (const float*)d_in[7];
  const float* dec_wih   = (const float*)d_in[8];
  const float* dec_whh   = (const float*)d_in[9];
  const float* dec_bih   = (const float*)d_in[10];
  const float* dec_bhh   = (const float*)d_in[11];
  const float* out_w     = (const float*)d_in[12];
  const float* out_b     = (const float*)d_in[13];
  const int*   sos_p     = (const int*)  d_in[14];
  const int*   eos_p     = (const int*)  d_in[15];

  char* ws = (char*)d_ws;
  float* gi_enc = (float*)ws;  ws += (size_t)SEQ_L * G3 * sizeof(float);
  float* gi_dec = (float*)ws;  ws += (size_t)SEQ_L * G3 * sizeof(float);
  float* hbuf   = (float*)ws;  ws += (size_t)(2 * SEQ_L + 1) * HID * sizeof(float);
  float* valid  = (float*)ws;  ws += SEQ_L * sizeof(float);
  int*   dec_in = (int*)ws;    ws += SEQ_L * sizeof(int);

  // decode step d (1..SEQ_L) writes hbuf row SEQ_L+d  ->  hdec = hbuf[SEQ_L+1]
  float* hdec = hbuf + (size_t)(SEQ_L + 1) * HID;

  float* out_scores = (float*)d_out;
  float* out_states = out_scores + (size_t)SEQ_L * VOCAB;

  prep_kernel<<<1, 1024, 0, stream>>>(target, sos_p, eos_p, dec_in, valid);
  gemm_nt<<<dim3(G3 / 128, SEQ_L / 128), 256, 0, stream>>>(
      emb, char_seq, enc_wih, enc_bih, nullptr, gi_enc, SEQ_L, G3, EMB);
  gemm_nt<<<dim3(G3 / 128, SEQ_L / 128), 256, 0, stream>>>(
      emb, dec_in, dec_wih, dec_bih, nullptr, gi_dec, SEQ_L, G3, EMB);
  recur_kernel<<<NWG, 1024, 0, stream>>>(
      enc_whh, enc_bhh, dec_whh, dec_bhh, enc_state, char_seq,
      gi_enc, gi_dec, hbuf);
  gemm_nt<<<dim3((VOCAB + 127) / 128, SEQ_L / 128), 256, 0, stream>>>(
      hdec, nullptr, out_w, out_b, valid, out_scores, SEQ_L, VOCAB, HID);
  states_kernel<<<(SEQ_L * HID) / 256, 256, 0, stream>>>(hdec, valid, out_states);
}